// Round 10
// baseline (1971.102 us; speedup 1.0000x reference)
//
#include <hip/hip_runtime.h>
#include <math.h>

typedef unsigned short u16;
typedef unsigned int u32;
typedef __attribute__((ext_vector_type(8))) short bf16x8;
typedef __attribute__((ext_vector_type(4))) float f32x4;

__device__ __forceinline__ float bf2f(u16 u) {
    union { u32 i; float f; } x; x.i = ((u32)u) << 16; return x.f;
}
__device__ __forceinline__ u16 f2bf(float f) {
    union { float f; u32 i; } x; x.f = f;
    u32 i = x.i;
    return (u16)((i + 0x7FFFu + ((i >> 16) & 1u)) >> 16);
}
__device__ __forceinline__ void async_copy16(void* lds, const void* g) {
    __builtin_amdgcn_global_load_lds(
        (const __attribute__((address_space(1))) void*)g,
        (__attribute__((address_space(3))) void*)lds, 16, 0, 0);
}
// tanh-form GELU (verified round 8): ~7 VALU ops, |err| ~3e-4.
__device__ __forceinline__ float gelu_fast(float v) {
    const float e = __expf(v * (1.5957691216f + 0.0713548162f * v * v));
    return v - v * __builtin_amdgcn_rcpf(e + 1.0f);
}

// f32 -> bf16 bulk convert; n must be divisible by 1024; grid = n/1024
__global__ __launch_bounds__(256) void conv_kernel(
    const float* __restrict__ in, u16* __restrict__ out)
{
    const int i = (blockIdx.x * 256 + threadIdx.x) * 4;
    float4 v = *(const float4*)&in[i];
    u32 lo = (u32)f2bf(v.x) | ((u32)f2bf(v.y) << 16);
    u32 hi = (u32)f2bf(v.z) | ((u32)f2bf(v.w) << 16);
    *(uint2*)&out[i] = make_uint2(lo, hi);
}

// pack bq,bk,bv -> [1536] f32; grid=6
__global__ __launch_bounds__(256) void pack_bias_kernel(
    const float* __restrict__ a, const float* __restrict__ b,
    const float* __restrict__ c, float* __restrict__ out)
{
    const int i = blockIdx.x * 256 + threadIdx.x;
    out[i] = i < 512 ? a[i] : (i < 1024 ? b[i - 512] : c[i - 1024]);
}

// ---------------------------------------------------------------------------
// 128x128-tile MFMA GEMM, m97 structure (single-buffered 2-barrier, 32 KB
// LDS -> 5 blocks/CU, 20 waves: cross-block TLP hides stage latency [m114]).
// C[M,N] = act(A @ B^T + bias)(+res). A,B bf16, staged via global_load_lds.
// Grid: 1D, nwg = ntm*ntn (nwg % 8 == 0). Chunked-bijective XCD swizzle:
// each XCD owns a contiguous wg range (distinct A rows -> A fetched once per
// XCD-L2), n-tile fastest within (A-tile reuse across the 4-16 n-tiles).
// ACT: 1 = fast GELU. OBF: 1 = bf16 out. RES: 0 none, 1 f32, 2 bf16.
// NSPLIT: 1 = N==1536 QKV split-write mode.
// ---------------------------------------------------------------------------
template<int ACT, int OBF, int RES, int NSPLIT>
__global__ __launch_bounds__(256) void gemm_kernel(
    const u16* __restrict__ Ag, const u16* __restrict__ Bg,
    const float* __restrict__ bias, const void* __restrict__ resv,
    void* __restrict__ Ov, u16* __restrict__ O2, u16* __restrict__ O3,
    int M, int N, int K)
{
    __shared__ u16 As[128 * 64];
    __shared__ u16 Bs[128 * 64];
    const int tid = threadIdx.x;
    const int lane = tid & 63;
    const int wm = (tid >> 7), wn = (tid >> 6) & 1;     // 2x2 waves
    const int li = lane & 15, g = lane >> 4;

    // chunked XCD swizzle: XCD x gets wg in [x*(nwg/8), (x+1)*(nwg/8))
    const int nwg = gridDim.x;
    const int wg = (blockIdx.x & 7) * (nwg >> 3) + (blockIdx.x >> 3);
    const int ntn = N >> 7;
    const int m0 = (wg / ntn) << 7;
    const int n0 = (wg % ntn) << 7;

    f32x4 acc[4][4] = {};

    for (int k0 = 0; k0 < K; k0 += 64) {
        // stage B tile [128 x 64] via global_load_lds (16B)
        {
            const int wbase = tid & 192;                 // wave*64
            #pragma unroll
            for (int i = 0; i < 4; ++i) {
                const int c = i * 256 + tid;             // chunk 0..1023
                const int row = c >> 3, cc = c & 7;
                async_copy16(&Bs[(size_t)(i * 256 + wbase) * 8],
                             &Bg[(size_t)(n0 + row) * K + k0 + cc * 8]);
                async_copy16(&As[(size_t)(i * 256 + wbase) * 8],
                             &Ag[(size_t)(m0 + row) * K + k0 + cc * 8]);
            }
        }
        __syncthreads();
        #pragma unroll
        for (int ks = 0; ks < 2; ++ks) {
            bf16x8 af[4], bf_[4];
            #pragma unroll
            for (int mi = 0; mi < 4; ++mi)
                af[mi] = *(const bf16x8*)&As[(wm * 64 + mi * 16 + li) * 64 + ks * 32 + g * 8];
            #pragma unroll
            for (int ni = 0; ni < 4; ++ni)
                bf_[ni] = *(const bf16x8*)&Bs[(wn * 64 + ni * 16 + li) * 64 + ks * 32 + g * 8];
            #pragma unroll
            for (int mi = 0; mi < 4; ++mi)
                #pragma unroll
                for (int ni = 0; ni < 4; ++ni)
                    acc[mi][ni] = __builtin_amdgcn_mfma_f32_16x16x32_bf16(
                        af[mi], bf_[ni], acc[mi][ni], 0, 0, 0);
        }
        __syncthreads();
    }

    #pragma unroll
    for (int mi = 0; mi < 4; ++mi)
    #pragma unroll
    for (int ni = 0; ni < 4; ++ni) {
        const int colb = n0 + wn * 64 + ni * 16;
        #pragma unroll
        for (int r = 0; r < 4; ++r) {
            const int row = m0 + wm * 64 + mi * 16 + g * 4 + r;
            const int col = colb + li;
            float v = acc[mi][ni][r] + bias[col];
            if (RES == 1) v += ((const float*)resv)[(size_t)row * N + col];
            if (RES == 2) v += bf2f(((const u16*)resv)[(size_t)row * N + col]);
            if (ACT == 1) v = gelu_fast(v);
            if (NSPLIT == 1) {
                const int sec = colb >> 9;
                u16* dst = sec == 0 ? (u16*)Ov : (sec == 1 ? O2 : O3);
                dst[(size_t)row * 512 + (col & 511)] = f2bf(v);
            } else if (OBF) {
                ((u16*)Ov)[(size_t)row * N + col] = f2bf(v);
            } else {
                ((float*)Ov)[(size_t)row * N + col] = v;
            }
        }
    }
}

// ---------------------------------------------------------------------------
// MFMA temporal attention (unchanged — verified).
// ---------------------------------------------------------------------------
__global__ __launch_bounds__(256) void attn_mfma_kernel(
    const u16* __restrict__ Q, const u16* __restrict__ K,
    const u16* __restrict__ V, const float* __restrict__ chan,
    u16* __restrict__ merged)
{
    __shared__ u16 pool[26112];          // 52,224 B
    u16* Ks = pool;                      // [128][72]   (dead after S)
    u16* Ps = pool;                      // [128][136]  overlays Ks
    u16* Vt = pool + 17408;              // [64][136]   V transposed
    const int b = blockIdx.x, h = blockIdx.y;
    const int tid = threadIdx.x, lane = tid & 63, w = tid >> 6;
    const int li = lane & 15, g = lane >> 4;
    const size_t gbase = (size_t)b * 128 * 512 + (size_t)h * 64;

    #pragma unroll
    for (int i = 0; i < 4; ++i) {
        const int c = tid + i * 256;     // 0..1023
        const int t = c >> 3, dc = c & 7;
        bf16x8 kv = *(const bf16x8*)&K[gbase + (size_t)t * 512 + dc * 8];
        *(bf16x8*)&Ks[t * 72 + dc * 8] = kv;
        bf16x8 vv = *(const bf16x8*)&V[gbase + (size_t)t * 512 + dc * 8];
        #pragma unroll
        for (int j = 0; j < 8; ++j) Vt[(dc * 8 + j) * 136 + t] = (u16)vv[j];
    }
    bf16x8 qf[2][2];
    #pragma unroll
    for (int mi = 0; mi < 2; ++mi)
        #pragma unroll
        for (int ks = 0; ks < 2; ++ks)
            qf[mi][ks] = *(const bf16x8*)
                &Q[gbase + (size_t)(w * 32 + mi * 16 + li) * 512 + ks * 32 + g * 8];
    __syncthreads();

    f32x4 sacc[2][8] = {};
    #pragma unroll
    for (int nj = 0; nj < 8; ++nj) {
        bf16x8 kf0 = *(const bf16x8*)&Ks[(nj * 16 + li) * 72 + g * 8];
        bf16x8 kf1 = *(const bf16x8*)&Ks[(nj * 16 + li) * 72 + 32 + g * 8];
        #pragma unroll
        for (int mi = 0; mi < 2; ++mi) {
            sacc[mi][nj] = __builtin_amdgcn_mfma_f32_16x16x32_bf16(
                qf[mi][0], kf0, sacc[mi][nj], 0, 0, 0);
            sacc[mi][nj] = __builtin_amdgcn_mfma_f32_16x16x32_bf16(
                qf[mi][1], kf1, sacc[mi][nj], 0, 0, 0);
        }
    }
    float linv[2][4];
    #pragma unroll
    for (int mi = 0; mi < 2; ++mi)
    #pragma unroll
    for (int r = 0; r < 4; ++r) {
        float mx = -1e30f;
        #pragma unroll
        for (int nj = 0; nj < 8; ++nj) {
            sacc[mi][nj][r] *= 0.125f;
            mx = fmaxf(mx, sacc[mi][nj][r]);
        }
        mx = fmaxf(mx, __shfl_xor(mx, 1));
        mx = fmaxf(mx, __shfl_xor(mx, 2));
        mx = fmaxf(mx, __shfl_xor(mx, 4));
        mx = fmaxf(mx, __shfl_xor(mx, 8));
        float l = 0.f;
        #pragma unroll
        for (int nj = 0; nj < 8; ++nj) {
            float p = __expf(sacc[mi][nj][r] - mx);
            sacc[mi][nj][r] = p;
            l += p;
        }
        l += __shfl_xor(l, 1);
        l += __shfl_xor(l, 2);
        l += __shfl_xor(l, 4);
        l += __shfl_xor(l, 8);
        linv[mi][r] = 1.f / l;
    }
    __syncthreads();
    #pragma unroll
    for (int mi = 0; mi < 2; ++mi)
    #pragma unroll
    for (int r = 0; r < 4; ++r)
        #pragma unroll
        for (int nj = 0; nj < 8; ++nj)
            Ps[(w * 32 + mi * 16 + g * 4 + r) * 136 + nj * 16 + li] =
                f2bf(sacc[mi][nj][r]);
    __syncthreads();

    f32x4 oacc[2][4] = {};
    #pragma unroll
    for (int ks = 0; ks < 4; ++ks) {
        bf16x8 pf[2];
        #pragma unroll
        for (int mi = 0; mi < 2; ++mi)
            pf[mi] = *(const bf16x8*)&Ps[(w * 32 + mi * 16 + li) * 136 + ks * 32 + g * 8];
        #pragma unroll
        for (int ni = 0; ni < 4; ++ni) {
            bf16x8 vf = *(const bf16x8*)&Vt[(ni * 16 + li) * 136 + ks * 32 + g * 8];
            #pragma unroll
            for (int mi = 0; mi < 2; ++mi)
                oacc[mi][ni] = __builtin_amdgcn_mfma_f32_16x16x32_bf16(
                    pf[mi], vf, oacc[mi][ni], 0, 0, 0);
        }
    }
    #pragma unroll
    for (int mi = 0; mi < 2; ++mi)
    #pragma unroll
    for (int ni = 0; ni < 4; ++ni)
    #pragma unroll
    for (int r = 0; r < 4; ++r) {
        const int row = w * 32 + mi * 16 + g * 4 + r;
        const int col = ni * 16 + li;
        float v = oacc[mi][ni][r] * linv[mi][r] +
                  chan[(size_t)b * 512 + h * 64 + col];
        merged[gbase + (size_t)row * 512 + col] = f2bf(v);
    }
}

// ---------------------------------------------------------------------------
// Channel-compression attention v2 (unchanged — verified).
// ---------------------------------------------------------------------------
__global__ __launch_bounds__(1024) void chan_oc_kernel(
    const u16* __restrict__ K, const u16* __restrict__ V,
    const u16* __restrict__ router_bf, float* __restrict__ oc)
{
    __shared__ float S[8 * 4096];        // 131072 B
    __shared__ float o_final[8 * 64];    // 2048 B
    __shared__ float linv[8];
    const int bs = blockIdx.x, h = blockIdx.y;
    const int tid = threadIdx.x, lane = tid & 63, w = tid >> 6;  // 16 waves
    const int li = lane & 15, g = lane >> 4;

    if (tid < 512) o_final[tid] = 0.f;

    bf16x8 af[2];
    #pragma unroll
    for (int ks = 0; ks < 2; ++ks) {
        bf16x8 t = {};
        if (li < 8) t = *(const bf16x8*)&router_bf[(h * 8 + li) * 64 + ks * 32 + g * 8];
        af[ks] = t;
    }
    #pragma unroll 4
    for (int n = w * 16; n < w * 16 + 16; ++n) {
        f32x4 acc = {};
        #pragma unroll
        for (int ks = 0; ks < 2; ++ks) {
            const int j = n * 16 + li;
            const int kc = j >> 7, kt = j & 127;
            bf16x8 bf_ = *(const bf16x8*)
                &K[((size_t)((bs * 32 + kc) * 128 + kt)) * 512 + h * 64 + ks * 32 + g * 8];
            acc = __builtin_amdgcn_mfma_f32_16x16x32_bf16(af[ks], bf_, acc, 0, 0, 0);
        }
        if (g < 2) {
            #pragma unroll
            for (int r = 0; r < 4; ++r)
                S[(g * 4 + r) * 4096 + n * 16 + li] = acc[r] * 0.125f;
        }
    }
    __syncthreads();
    if (w < 8) {
        float l = 0.f;
        #pragma unroll 8
        for (int i = 0; i < 64; ++i) {
            float p = __expf(S[w * 4096 + i * 64 + lane]);
            S[w * 4096 + i * 64 + lane] = p;
            l += p;
        }
        #pragma unroll
        for (int off = 1; off < 64; off <<= 1) l += __shfl_xor(l, off);
        if (lane == 0) linv[w] = 1.f / l;
    }
    __syncthreads();
    float o[8][4] = {};
    for (int it = 0; it < 64; ++it) {
        const int row = w * 256 + it * 4 + g;        // = c*128 + t
        const int j = (row & 127) * 32 + (row >> 7); // P index (t*32+c)
        const uint2 vv = *(const uint2*)
            &V[((size_t)bs * 4096 + row) * 512 + h * 64 + li * 4];
        const float v0 = bf2f((u16)(vv.x & 0xffff)), v1 = bf2f((u16)(vv.x >> 16));
        const float v2 = bf2f((u16)(vv.y & 0xffff)), v3 = bf2f((u16)(vv.y >> 16));
        #pragma unroll
        for (int q = 0; q < 8; ++q) {
            const float p = S[q * 4096 + j];
            o[q][0] += p * v0; o[q][1] += p * v1;
            o[q][2] += p * v2; o[q][3] += p * v3;
        }
    }
    #pragma unroll
    for (int q = 0; q < 8; ++q)
        #pragma unroll
        for (int i = 0; i < 4; ++i) {
            float v = o[q][i];
            v += __shfl_xor(v, 16);
            v += __shfl_xor(v, 32);
            if (g == 0) atomicAdd(&o_final[q * 64 + li * 4 + i], v);
        }
    __syncthreads();
    if (tid < 512) {
        const int q = tid >> 6, d = tid & 63;
        oc[((size_t)bs * 8 + q) * 512 + h * 64 + d] = o_final[q * 64 + d] * linv[q];
    }
}

__global__ __launch_bounds__(512) void chan_combine_kernel(
    const float* __restrict__ oc, const float* __restrict__ pos,
    const float* __restrict__ mexp, float* __restrict__ chan)
{
    const int b = blockIdx.x;
    const int bs = b >> 5, c = b & 31;
    const int d = threadIdx.x;
    float acc = 0.f;
    #pragma unroll
    for (int q = 0; q < 8; ++q)
        acc += mexp[c * 8 + q] *
               (oc[((size_t)bs * 8 + q) * 512 + d] + pos[q * 512 + d]);
    chan[(size_t)b * 512 + d] = acc;
}

// LayerNorm over 512. One wave per row, 4 rows/block.
// IBF: 1 = bf16 input. OBF: 1 = bf16 out.
template<int IBF, int OBF>
__global__ __launch_bounds__(256) void ln_kernel(
    const void* __restrict__ inv, const float* __restrict__ g,
    const float* __restrict__ bb, void* __restrict__ out)
{
    const size_t row = (size_t)blockIdx.x * 4 + (threadIdx.x >> 6);
    const int t = threadIdx.x & 63;
    float4 v0, v1;
    if (IBF) {
        const u16* p = (const u16*)inv + row * 512;
        uint2 a = *(const uint2*)(p + t * 4);
        uint2 b = *(const uint2*)(p + 256 + t * 4);
        v0 = make_float4(bf2f((u16)(a.x & 0xffff)), bf2f((u16)(a.x >> 16)),
                         bf2f((u16)(a.y & 0xffff)), bf2f((u16)(a.y >> 16)));
        v1 = make_float4(bf2f((u16)(b.x & 0xffff)), bf2f((u16)(b.x >> 16)),
                         bf2f((u16)(b.y & 0xffff)), bf2f((u16)(b.y >> 16)));
    } else {
        const float* p = (const float*)inv + row * 512;
        v0 = *(const float4*)(p + t * 4);
        v1 = *(const float4*)(p + 256 + t * 4);
    }
    float s = (v0.x + v0.y) + (v0.z + v0.w) + (v1.x + v1.y) + (v1.z + v1.w);
    #pragma unroll
    for (int off = 1; off < 64; off <<= 1) s += __shfl_xor(s, off);
    const float mean = s * (1.0f / 512.0f);
    float a, ss = 0.f;
    a = v0.x - mean; ss += a * a;  a = v0.y - mean; ss += a * a;
    a = v0.z - mean; ss += a * a;  a = v0.w - mean; ss += a * a;
    a = v1.x - mean; ss += a * a;  a = v1.y - mean; ss += a * a;
    a = v1.z - mean; ss += a * a;  a = v1.w - mean; ss += a * a;
    #pragma unroll
    for (int off = 1; off < 64; off <<= 1) ss += __shfl_xor(ss, off);
    const float rstd = rsqrtf(ss * (1.0f / 512.0f) + 1e-5f);
    const int c0 = t * 4, c1 = 256 + t * 4;
    float4 g0 = *(const float4*)(g + c0), g1v = *(const float4*)(g + c1);
    float4 b0 = *(const float4*)(bb + c0), b1v = *(const float4*)(bb + c1);
    float r0 = (v0.x - mean) * rstd * g0.x + b0.x;
    float r1 = (v0.y - mean) * rstd * g0.y + b0.y;
    float r2 = (v0.z - mean) * rstd * g0.z + b0.z;
    float r3 = (v0.w - mean) * rstd * g0.w + b0.w;
    float r4 = (v1.x - mean) * rstd * g1v.x + b1v.x;
    float r5 = (v1.y - mean) * rstd * g1v.y + b1v.y;
    float r6 = (v1.z - mean) * rstd * g1v.z + b1v.z;
    float r7 = (v1.w - mean) * rstd * g1v.w + b1v.w;
    if (OBF) {
        u16* ob = (u16*)out + row * 512;
        uint2 u0, u1;
        u0.x = (u32)f2bf(r0) | ((u32)f2bf(r1) << 16);
        u0.y = (u32)f2bf(r2) | ((u32)f2bf(r3) << 16);
        u1.x = (u32)f2bf(r4) | ((u32)f2bf(r5) << 16);
        u1.y = (u32)f2bf(r6) | ((u32)f2bf(r7) << 16);
        *(uint2*)(ob + c0) = u0;
        *(uint2*)(ob + c1) = u1;
    } else {
        float* of = (float*)out + row * 512;
        *(float4*)(of + c0) = make_float4(r0, r1, r2, r3);
        *(float4*)(of + c1) = make_float4(r4, r5, r6, r7);
    }
}

// ---------------------------------------------------------------------------
extern "C" void kernel_launch(void* const* d_in, const int* in_sizes, int n_in,
                              void* d_out, int out_size, void* d_ws, size_t ws_size,
                              hipStream_t stream)
{
    const float* src    = (const float*)d_in[0];
    const float* Wq     = (const float*)d_in[1];
    const float* bq     = (const float*)d_in[2];
    const float* Wk     = (const float*)d_in[3];
    const float* bk     = (const float*)d_in[4];
    const float* Wv     = (const float*)d_in[5];
    const float* bv     = (const float*)d_in[6];
    const float* Wo     = (const float*)d_in[7];
    const float* bo     = (const float*)d_in[8];
    const float* router = (const float*)d_in[9];
    const float* mexp   = (const float*)d_in[10];
    const float* pos    = (const float*)d_in[11];
    const float* g1     = (const float*)d_in[12];
    const float* b1     = (const float*)d_in[13];
    const float* Wf1    = (const float*)d_in[14];
    const float* bf1    = (const float*)d_in[15];
    const float* Wf2    = (const float*)d_in[16];
    const float* bf2_   = (const float*)d_in[17];
    const float* g2     = (const float*)d_in[18];
    const float* b2     = (const float*)d_in[19];

    float* out = (float*)d_out;   // final f32 (written by LN2)

    char* ws = (char*)d_ws;
    // ws layout (bytes). Peak ~547.4 MB (same proven budget).
    u16*   Qb     = (u16*)(ws + 0);              // 134217728
    u16*   Kb     = (u16*)(ws + 134217728);      // 134217728
    u16*   Vb     = (u16*)(ws + 268435456);      // 134217728
    u16*   merged = (u16*)(ws + 402653184);      // 134217728
    float* oc     = (float*)(ws + 536870912);    // 524288
    float* chan   = (float*)(ws + 537395200);    // 2097152
    u16*   wob    = (u16*)(ws + 541065216);      // 524288
    u16*   wf1b   = (u16*)(ws + 541589504);      // 2097152
    u16*   wf2b   = (u16*)(ws + 543686656);      // 2097152
    u16*   wqkvb  = (u16*)(ws + 545783808);      // 1572864
    float* qkvbias= (float*)(ws + 547356672);    // 6144
    u16*   routbf = (u16*)(ws + 547362816);      // 8192 (ends 547371008)
    // overlays (liveness-checked):
    u16*   srcb   = (u16*)(ws + 402653184);      // bf16 src (over merged;
                                                 //  dead before attn writes)
    u16*   h1b    = (u16*)(ws + 134217728);      // bf16 h1 (over Kb; dead after LN1)
    u16*   xb     = (u16*)(ws + 0);              // bf16 LN1 out (over Qb)
    u16*   gbuf   = (u16*)(ws + 268435456);      // bf16 gelu chunk 134 MB
                                                 //  (over Vb; L3-resident FF1->FF2)
    u16*   h2b    = (u16*)(ws + 134217728);      // bf16 h2 (over Kb/h1b)

    const dim3 blk(256);
    // conversions / packing
    conv_kernel<<<dim3(65536), blk, 0, stream>>>(src, srcb);
    conv_kernel<<<dim3(256),  blk, 0, stream>>>(Wq,  wqkvb);
    conv_kernel<<<dim3(256),  blk, 0, stream>>>(Wk,  wqkvb + 262144);
    conv_kernel<<<dim3(256),  blk, 0, stream>>>(Wv,  wqkvb + 524288);
    conv_kernel<<<dim3(256),  blk, 0, stream>>>(Wo,  wob);
    conv_kernel<<<dim3(1024), blk, 0, stream>>>(Wf1, wf1b);
    conv_kernel<<<dim3(1024), blk, 0, stream>>>(Wf2, wf2b);
    conv_kernel<<<dim3(4),    blk, 0, stream>>>(router, routbf);
    pack_bias_kernel<<<dim3(6), blk, 0, stream>>>(bq, bk, bv, qkvbias);
    // fused QKV projection: nwg = 1024 m-tiles * 12 n-tiles = 12288
    gemm_kernel<0, 1, 0, 1><<<dim3(12288), blk, 0, stream>>>(
        srcb, wqkvb, qkvbias, nullptr, Qb, Kb, Vb, 131072, 1536, 512);
    // channel path (attn epilogue consumes chan)
    chan_oc_kernel<<<dim3(32, 8), dim3(1024), 0, stream>>>(Kb, Vb, routbf, oc);
    chan_combine_kernel<<<dim3(1024), dim3(512), 0, stream>>>(oc, pos, mexp, chan);
    // temporal attention (+chan) -> merged bf16
    attn_mfma_kernel<<<dim3(1024, 8), blk, 0, stream>>>(Qb, Kb, Vb, chan, merged);
    // h1 = src + merged @ Wo^T + bo -> h1b bf16; nwg = 1024*4 = 4096
    gemm_kernel<0, 1, 1, 0><<<dim3(4096), blk, 0, stream>>>(
        merged, wob, bo, src, h1b, nullptr, nullptr, 131072, 512, 512);
    // x = LN1(h1) -> bf16
    ln_kernel<1, 1><<<dim3(32768), blk, 0, stream>>>(h1b, g1, b1, xb);
    // FF in 4 chunks of 32768 rows (gbuf L3-resident between FF1/FF2)
    for (int c = 0; c < 4; ++c) {
        const size_t off = (size_t)c * 32768 * 512;
        // g = gelu(x @ Wf1^T + bf1) -> gbuf bf16; nwg = 256*16 = 4096
        gemm_kernel<1, 1, 0, 0><<<dim3(4096), blk, 0, stream>>>(
            xb + off, wf1b, bf1, nullptr, gbuf, nullptr, nullptr,
            32768, 2048, 512);
        // h2 = x + g @ Wf2^T + bf2 -> h2b bf16; nwg = 256*4 = 1024
        gemm_kernel<0, 1, 2, 0><<<dim3(1024), blk, 0, stream>>>(
            gbuf, wf2b, bf2_, xb + off, h2b + off, nullptr, nullptr,
            32768, 512, 2048);
    }
    // out = LN2(h2) -> d_out f32
    ln_kernel<1, 0><<<dim3(32768), blk, 0, stream>>>(h2b, g2, b2, out);
}

// Round 12
// 1513.204 us; speedup vs baseline: 1.3026x; 1.3026x over previous
//
#include <hip/hip_runtime.h>
#include <math.h>

typedef unsigned short u16;
typedef unsigned int u32;
typedef __attribute__((ext_vector_type(8))) short bf16x8;
typedef __attribute__((ext_vector_type(4))) float f32x4;

__device__ __forceinline__ float bf2f(u16 u) {
    union { u32 i; float f; } x; x.i = ((u32)u) << 16; return x.f;
}
__device__ __forceinline__ u16 f2bf(float f) {
    union { float f; u32 i; } x; x.f = f;
    u32 i = x.i;
    return (u16)((i + 0x7FFFu + ((i >> 16) & 1u)) >> 16);
}
__device__ __forceinline__ void async_copy16(void* lds, const void* g) {
    __builtin_amdgcn_global_load_lds(
        (const __attribute__((address_space(1))) void*)g,
        (__attribute__((address_space(3))) void*)lds, 16, 0, 0);
}
// tanh-form GELU (verified round 8): ~7 VALU ops, |err| ~3e-4.
__device__ __forceinline__ float gelu_fast(float v) {
    const float e = __expf(v * (1.5957691216f + 0.0713548162f * v * v));
    return v - v * __builtin_amdgcn_rcpf(e + 1.0f);
}

// ---------------------------------------------------------------------------
// Fused f32->bf16 conversion for all tensors (1 launch replaces 8).
// Block ranges: [0,256) Wq, [256,512) Wk, [512,768) Wv, [768,1024) Wo,
// [1024,2048) Wf1, [2048,3072) Wf2, [3072,3076) router, [3076,..) src.
// Each block converts 1024 elements.
// ---------------------------------------------------------------------------
__global__ __launch_bounds__(256) void convall_kernel(
    const float* __restrict__ src, const float* __restrict__ Wq,
    const float* __restrict__ Wk,  const float* __restrict__ Wv,
    const float* __restrict__ Wo,  const float* __restrict__ Wf1,
    const float* __restrict__ Wf2, const float* __restrict__ router,
    u16* __restrict__ srcb, u16* __restrict__ wqkvb, u16* __restrict__ wob,
    u16* __restrict__ wf1b, u16* __restrict__ wf2b, u16* __restrict__ routbf)
{
    const int b = blockIdx.x;
    const float* in; u16* out; int off;
    if      (b < 256)  { in = Wq;     out = wqkvb;          off = b; }
    else if (b < 512)  { in = Wk;     out = wqkvb + 262144; off = b - 256; }
    else if (b < 768)  { in = Wv;     out = wqkvb + 524288; off = b - 512; }
    else if (b < 1024) { in = Wo;     out = wob;            off = b - 768; }
    else if (b < 2048) { in = Wf1;    out = wf1b;           off = b - 1024; }
    else if (b < 3072) { in = Wf2;    out = wf2b;           off = b - 2048; }
    else if (b < 3076) { in = router; out = routbf;         off = b - 3072; }
    else               { in = src;    out = srcb;           off = b - 3076; }
    const size_t i = ((size_t)off * 256 + threadIdx.x) * 4;
    float4 v = *(const float4*)&in[i];
    u32 lo = (u32)f2bf(v.x) | ((u32)f2bf(v.y) << 16);
    u32 hi = (u32)f2bf(v.z) | ((u32)f2bf(v.w) << 16);
    *(uint2*)&out[i] = make_uint2(lo, hi);
}

// pack bq,bk,bv -> [1536] f32; grid=6
__global__ __launch_bounds__(256) void pack_bias_kernel(
    const float* __restrict__ a, const float* __restrict__ b,
    const float* __restrict__ c, float* __restrict__ out)
{
    const int i = blockIdx.x * 256 + threadIdx.x;
    out[i] = i < 512 ? a[i] : (i < 1024 ? b[i - 512] : c[i - 1024]);
}

// ---------------------------------------------------------------------------
// 256x256-tile, 8-wave MFMA GEMM with counted-vmcnt K-half pipeline (T3/T4).
// (verified rounds 7-8: best structure at our K; 698 TF on QKV)
// Waits: vmcnt(4)+s_barrier at P1/P3 only -> 4 loads always in flight.
// LDS K-half layout: slot(row,c) = (row>>1)*8 + ((((row&1)<<2)|c)^((row>>1)&7))
// -> gload-contiguous halves, 2-way bank aliasing (free). Rule #21 respected.
// ACT: 1 = fast GELU. OBF: 1 = bf16 out. RES: 0 none, 1 f32, 2 bf16.
// NSPLIT: 1 = N==1536 QKV split-write mode.
// Grid: 1D, nwg % 8 == 0, XCD-swizzled, n-tile fastest.
// ---------------------------------------------------------------------------
template<int ACT, int OBF, int RES, int NSPLIT>
__global__ __launch_bounds__(512) void gemm256_kernel(
    const u16* __restrict__ Ag, const u16* __restrict__ Bg,
    const float* __restrict__ bias, const void* __restrict__ resv,
    void* __restrict__ Ov, u16* __restrict__ O2, u16* __restrict__ O3,
    int M, int N, int K)
{
    __shared__ u16 As[2][2][8192];   // [buf][khalf][1024 slots * 8 u16]
    __shared__ u16 Bs[2][2][8192];
    const int tid = threadIdx.x;
    const int lane = tid & 63;
    const int wm = tid >> 8, wn = (tid >> 6) & 3;     // 2x4 waves
    const int li = lane & 15, g = lane >> 4;

    const int nwg = gridDim.x;
    const int wg = ((blockIdx.x & 7) * (nwg >> 3)) + (blockIdx.x >> 3);
    const int ntn = N >> 8;
    const int m0 = (wg / ntn) << 8;
    const int n0 = (wg % ntn) << 8;

    // staging sources (per-thread constants; add k-offset per tile)
    const u16 *sa0, *sa1, *sb0, *sb1;
    {
        int L = tid, p = L >> 3, q = L & 7, u = q ^ (p & 7);
        int row = 2 * p + (u >> 2), c = u & 3;
        sa0 = Ag + (size_t)(m0 + row) * K + c * 8;
        sb0 = Bg + (size_t)(n0 + row) * K + c * 8;
        L = 512 + tid; p = L >> 3; q = L & 7; u = q ^ (p & 7);
        row = 2 * p + (u >> 2); c = u & 3;
        sa1 = Ag + (size_t)(m0 + row) * K + c * 8;
        sb1 = Bg + (size_t)(n0 + row) * K + c * 8;
    }
    // LDS dest bases (wave-uniform; HW adds lane*16B)
    const int db0 = (tid & 448) * 8;            // round 0: slots [wave*64 ..]
    const int db1 = (512 + (tid & 448)) * 8;    // round 1

    // fragment LDS offsets (u16 units), per-thread constants
    int offA[8], offB[4];
    #pragma unroll
    for (int i = 0; i < 8; ++i) {
        const int row = wm * 128 + i * 16 + li;
        const int p = row >> 1;
        offA[i] = (p * 8 + ((((row & 1) << 2) | g) ^ (p & 7))) * 8;
    }
    #pragma unroll
    for (int i = 0; i < 4; ++i) {
        const int row = wn * 64 + i * 16 + li;
        const int p = row >> 1;
        offB[i] = (p * 8 + ((((row & 1) << 2) | g) ^ (p & 7))) * 8;
    }

    f32x4 acc[8][4] = {};
    const int nk = K >> 6;

#define STAGE_A(buf, ks, kc) do { \
    async_copy16(&As[buf][ks][db0], sa0 + (kc)); \
    async_copy16(&As[buf][ks][db1], sa1 + (kc)); } while (0)
#define STAGE_B(buf, ks, kc) do { \
    async_copy16(&Bs[buf][ks][db0], sb0 + (kc)); \
    async_copy16(&Bs[buf][ks][db1], sb1 + (kc)); } while (0)

    // prologue: tile 0 -> buf 0 (issue order: A-K0, B-K0, A-K1, B-K1)
    STAGE_A(0, 0, 0); STAGE_B(0, 0, 0);
    STAGE_A(0, 1, 32); STAGE_B(0, 1, 32);

    for (int t = 0; t < nk; ++t) {
        const int cur = t & 1, nxt = cur ^ 1;
        const int kn = (t + 1 < nk ? t + 1 : t) << 6;  // clamped (uniform counts)
        bf16x8 af[4], bfr[4];

        // ---- P1: consume A-K0,B-K0 of tile t ----
        asm volatile("s_waitcnt vmcnt(4)" ::: "memory");
        __builtin_amdgcn_s_barrier();
        STAGE_A(nxt, 0, kn);
        #pragma unroll
        for (int i = 0; i < 4; ++i) af[i]  = *(const bf16x8*)&As[cur][0][offA[i]];
        #pragma unroll
        for (int i = 0; i < 4; ++i) bfr[i] = *(const bf16x8*)&Bs[cur][0][offB[i]];
        __builtin_amdgcn_s_setprio(1);
        #pragma unroll
        for (int mi = 0; mi < 4; ++mi)
            #pragma unroll
            for (int ni = 0; ni < 4; ++ni)
                acc[mi][ni] = __builtin_amdgcn_mfma_f32_16x16x32_bf16(
                    af[mi], bfr[ni], acc[mi][ni], 0, 0, 0);
        __builtin_amdgcn_s_setprio(0);

        // ---- P2: rows 128-255 @ K0 (B regs reused) ----
        STAGE_B(nxt, 0, kn);
        #pragma unroll
        for (int i = 0; i < 4; ++i) af[i] = *(const bf16x8*)&As[cur][0][offA[4 + i]];
        __builtin_amdgcn_s_setprio(1);
        #pragma unroll
        for (int mi = 0; mi < 4; ++mi)
            #pragma unroll
            for (int ni = 0; ni < 4; ++ni)
                acc[4 + mi][ni] = __builtin_amdgcn_mfma_f32_16x16x32_bf16(
                    af[mi], bfr[ni], acc[4 + mi][ni], 0, 0, 0);
        __builtin_amdgcn_s_setprio(0);

        // ---- P3: consume A-K1,B-K1 of tile t ----
        asm volatile("s_waitcnt vmcnt(4)" ::: "memory");
        __builtin_amdgcn_s_barrier();
        STAGE_A(nxt, 1, kn + 32);
        #pragma unroll
        for (int i = 0; i < 4; ++i) af[i]  = *(const bf16x8*)&As[cur][1][offA[i]];
        #pragma unroll
        for (int i = 0; i < 4; ++i) bfr[i] = *(const bf16x8*)&Bs[cur][1][offB[i]];
        __builtin_amdgcn_s_setprio(1);
        #pragma unroll
        for (int mi = 0; mi < 4; ++mi)
            #pragma unroll
            for (int ni = 0; ni < 4; ++ni)
                acc[mi][ni] = __builtin_amdgcn_mfma_f32_16x16x32_bf16(
                    af[mi], bfr[ni], acc[mi][ni], 0, 0, 0);
        __builtin_amdgcn_s_setprio(0);

        // ---- P4: rows 128-255 @ K1 ----
        STAGE_B(nxt, 1, kn + 32);
        #pragma unroll
        for (int i = 0; i < 4; ++i) af[i] = *(const bf16x8*)&As[cur][1][offA[4 + i]];
        __builtin_amdgcn_s_setprio(1);
        #pragma unroll
        for (int mi = 0; mi < 4; ++mi)
            #pragma unroll
            for (int ni = 0; ni < 4; ++ni)
                acc[4 + mi][ni] = __builtin_amdgcn_mfma_f32_16x16x32_bf16(
                    af[mi], bfr[ni], acc[4 + mi][ni], 0, 0, 0);
        __builtin_amdgcn_s_setprio(0);
    }
    asm volatile("s_waitcnt vmcnt(0)" ::: "memory");
#undef STAGE_A
#undef STAGE_B

    #pragma unroll
    for (int mi = 0; mi < 8; ++mi)
    #pragma unroll
    for (int ni = 0; ni < 4; ++ni) {
        const int colb = n0 + wn * 64 + ni * 16;
        #pragma unroll
        for (int r = 0; r < 4; ++r) {
            const int row = m0 + wm * 128 + mi * 16 + g * 4 + r;
            const int col = colb + li;
            float v = acc[mi][ni][r] + bias[col];
            if (RES == 1) v += ((const float*)resv)[(size_t)row * N + col];
            if (RES == 2) v += bf2f(((const u16*)resv)[(size_t)row * N + col]);
            if (ACT == 1) v = gelu_fast(v);
            if (NSPLIT == 1) {
                const int sec = colb >> 9;
                u16* dst = sec == 0 ? (u16*)Ov : (sec == 1 ? O2 : O3);
                dst[(size_t)row * 512 + (col & 511)] = f2bf(v);
            } else if (OBF) {
                ((u16*)Ov)[(size_t)row * N + col] = f2bf(v);
            } else {
                ((float*)Ov)[(size_t)row * N + col] = v;
            }
        }
    }
}

// ---------------------------------------------------------------------------
// MFMA temporal attention (unchanged — verified). NOTE: `merged` may alias
// `Q` (write-after-read, same (b,h) slice): all Q reads in a block complete
// before its S-phase MFMAs, which precede the Ps-write + __syncthreads that
// gates every epilogue write. Cross-block slices are disjoint.
// ---------------------------------------------------------------------------
__global__ __launch_bounds__(256) void attn_mfma_kernel(
    const u16* __restrict__ Q, const u16* __restrict__ K,
    const u16* __restrict__ V, const float* __restrict__ chan,
    u16* __restrict__ merged)
{
    __shared__ u16 pool[26112];          // 52,224 B
    u16* Ks = pool;                      // [128][72]   (dead after S)
    u16* Ps = pool;                      // [128][136]  overlays Ks
    u16* Vt = pool + 17408;              // [64][136]   V transposed
    const int b = blockIdx.x, h = blockIdx.y;
    const int tid = threadIdx.x, lane = tid & 63, w = tid >> 6;
    const int li = lane & 15, g = lane >> 4;
    const size_t gbase = (size_t)b * 128 * 512 + (size_t)h * 64;

    #pragma unroll
    for (int i = 0; i < 4; ++i) {
        const int c = tid + i * 256;     // 0..1023
        const int t = c >> 3, dc = c & 7;
        bf16x8 kv = *(const bf16x8*)&K[gbase + (size_t)t * 512 + dc * 8];
        *(bf16x8*)&Ks[t * 72 + dc * 8] = kv;
        bf16x8 vv = *(const bf16x8*)&V[gbase + (size_t)t * 512 + dc * 8];
        #pragma unroll
        for (int j = 0; j < 8; ++j) Vt[(dc * 8 + j) * 136 + t] = (u16)vv[j];
    }
    bf16x8 qf[2][2];
    #pragma unroll
    for (int mi = 0; mi < 2; ++mi)
        #pragma unroll
        for (int ks = 0; ks < 2; ++ks)
            qf[mi][ks] = *(const bf16x8*)
                &Q[gbase + (size_t)(w * 32 + mi * 16 + li) * 512 + ks * 32 + g * 8];
    __syncthreads();

    f32x4 sacc[2][8] = {};
    #pragma unroll
    for (int nj = 0; nj < 8; ++nj) {
        bf16x8 kf0 = *(const bf16x8*)&Ks[(nj * 16 + li) * 72 + g * 8];
        bf16x8 kf1 = *(const bf16x8*)&Ks[(nj * 16 + li) * 72 + 32 + g * 8];
        #pragma unroll
        for (int mi = 0; mi < 2; ++mi) {
            sacc[mi][nj] = __builtin_amdgcn_mfma_f32_16x16x32_bf16(
                qf[mi][0], kf0, sacc[mi][nj], 0, 0, 0);
            sacc[mi][nj] = __builtin_amdgcn_mfma_f32_16x16x32_bf16(
                qf[mi][1], kf1, sacc[mi][nj], 0, 0, 0);
        }
    }
    float linv[2][4];
    #pragma unroll
    for (int mi = 0; mi < 2; ++mi)
    #pragma unroll
    for (int r = 0; r < 4; ++r) {
        float mx = -1e30f;
        #pragma unroll
        for (int nj = 0; nj < 8; ++nj) {
            sacc[mi][nj][r] *= 0.125f;
            mx = fmaxf(mx, sacc[mi][nj][r]);
        }
        mx = fmaxf(mx, __shfl_xor(mx, 1));
        mx = fmaxf(mx, __shfl_xor(mx, 2));
        mx = fmaxf(mx, __shfl_xor(mx, 4));
        mx = fmaxf(mx, __shfl_xor(mx, 8));
        float l = 0.f;
        #pragma unroll
        for (int nj = 0; nj < 8; ++nj) {
            float p = __expf(sacc[mi][nj][r] - mx);
            sacc[mi][nj][r] = p;
            l += p;
        }
        l += __shfl_xor(l, 1);
        l += __shfl_xor(l, 2);
        l += __shfl_xor(l, 4);
        l += __shfl_xor(l, 8);
        linv[mi][r] = 1.f / l;
    }
    __syncthreads();
    #pragma unroll
    for (int mi = 0; mi < 2; ++mi)
    #pragma unroll
    for (int r = 0; r < 4; ++r)
        #pragma unroll
        for (int nj = 0; nj < 8; ++nj)
            Ps[(w * 32 + mi * 16 + g * 4 + r) * 136 + nj * 16 + li] =
                f2bf(sacc[mi][nj][r]);
    __syncthreads();

    f32x4 oacc[2][4] = {};
    #pragma unroll
    for (int ks = 0; ks < 4; ++ks) {
        bf16x8 pf[2];
        #pragma unroll
        for (int mi = 0; mi < 2; ++mi)
            pf[mi] = *(const bf16x8*)&Ps[(w * 32 + mi * 16 + li) * 136 + ks * 32 + g * 8];
        #pragma unroll
        for (int ni = 0; ni < 4; ++ni) {
            bf16x8 vf = *(const bf16x8*)&Vt[(ni * 16 + li) * 136 + ks * 32 + g * 8];
            #pragma unroll
            for (int mi = 0; mi < 2; ++mi)
                oacc[mi][ni] = __builtin_amdgcn_mfma_f32_16x16x32_bf16(
                    pf[mi], vf, oacc[mi][ni], 0, 0, 0);
        }
    }
    #pragma unroll
    for (int mi = 0; mi < 2; ++mi)
    #pragma unroll
    for (int ni = 0; ni < 4; ++ni)
    #pragma unroll
    for (int r = 0; r < 4; ++r) {
        const int row = w * 32 + mi * 16 + g * 4 + r;
        const int col = ni * 16 + li;
        float v = oacc[mi][ni][r] * linv[mi][r] +
                  chan[(size_t)b * 512 + h * 64 + col];
        merged[gbase + (size_t)row * 512 + col] = f2bf(v);
    }
}

// ---------------------------------------------------------------------------
// Channel-compression attention v2 (unchanged — verified).
// ---------------------------------------------------------------------------
__global__ __launch_bounds__(1024) void chan_oc_kernel(
    const u16* __restrict__ K, const u16* __restrict__ V,
    const u16* __restrict__ router_bf, float* __restrict__ oc)
{
    __shared__ float S[8 * 4096];        // 131072 B
    __shared__ float o_final[8 * 64];    // 2048 B
    __shared__ float linv[8];
    const int bs = blockIdx.x, h = blockIdx.y;
    const int tid = threadIdx.x, lane = tid & 63, w = tid >> 6;  // 16 waves
    const int li = lane & 15, g = lane >> 4;

    if (tid < 512) o_final[tid] = 0.f;

    bf16x8 af[2];
    #pragma unroll
    for (int ks = 0; ks < 2; ++ks) {
        bf16x8 t = {};
        if (li < 8) t = *(const bf16x8*)&router_bf[(h * 8 + li) * 64 + ks * 32 + g * 8];
        af[ks] = t;
    }
    #pragma unroll 4
    for (int n = w * 16; n < w * 16 + 16; ++n) {
        f32x4 acc = {};
        #pragma unroll
        for (int ks = 0; ks < 2; ++ks) {
            const int j = n * 16 + li;
            const int kc = j >> 7, kt = j & 127;
            bf16x8 bf_ = *(const bf16x8*)
                &K[((size_t)((bs * 32 + kc) * 128 + kt)) * 512 + h * 64 + ks * 32 + g * 8];
            acc = __builtin_amdgcn_mfma_f32_16x16x32_bf16(af[ks], bf_, acc, 0, 0, 0);
        }
        if (g < 2) {
            #pragma unroll
            for (int r = 0; r < 4; ++r)
                S[(g * 4 + r) * 4096 + n * 16 + li] = acc[r] * 0.125f;
        }
    }
    __syncthreads();
    if (w < 8) {
        float l = 0.f;
        #pragma unroll 8
        for (int i = 0; i < 64; ++i) {
            float p = __expf(S[w * 4096 + i * 64 + lane]);
            S[w * 4096 + i * 64 + lane] = p;
            l += p;
        }
        #pragma unroll
        for (int off = 1; off < 64; off <<= 1) l += __shfl_xor(l, off);
        if (lane == 0) linv[w] = 1.f / l;
    }
    __syncthreads();
    float o[8][4] = {};
    for (int it = 0; it < 64; ++it) {
        const int row = w * 256 + it * 4 + g;        // = c*128 + t
        const int j = (row & 127) * 32 + (row >> 7); // P index (t*32+c)
        const uint2 vv = *(const uint2*)
            &V[((size_t)bs * 4096 + row) * 512 + h * 64 + li * 4];
        const float v0 = bf2f((u16)(vv.x & 0xffff)), v1 = bf2f((u16)(vv.x >> 16));
        const float v2 = bf2f((u16)(vv.y & 0xffff)), v3 = bf2f((u16)(vv.y >> 16));
        #pragma unroll
        for (int q = 0; q < 8; ++q) {
            const float p = S[q * 4096 + j];
            o[q][0] += p * v0; o[q][1] += p * v1;
            o[q][2] += p * v2; o[q][3] += p * v3;
        }
    }
    #pragma unroll
    for (int q = 0; q < 8; ++q)
        #pragma unroll
        for (int i = 0; i < 4; ++i) {
            float v = o[q][i];
            v += __shfl_xor(v, 16);
            v += __shfl_xor(v, 32);
            if (g == 0) atomicAdd(&o_final[q * 64 + li * 4 + i], v);
        }
    __syncthreads();
    if (tid < 512) {
        const int q = tid >> 6, d = tid & 63;
        oc[((size_t)bs * 8 + q) * 512 + h * 64 + d] = o_final[q * 64 + d] * linv[q];
    }
}

__global__ __launch_bounds__(512) void chan_combine_kernel(
    const float* __restrict__ oc, const float* __restrict__ pos,
    const float* __restrict__ mexp, float* __restrict__ chan)
{
    const int b = blockIdx.x;
    const int bs = b >> 5, c = b & 31;
    const int d = threadIdx.x;
    float acc = 0.f;
    #pragma unroll
    for (int q = 0; q < 8; ++q)
        acc += mexp[c * 8 + q] *
               (oc[((size_t)bs * 8 + q) * 512 + d] + pos[q * 512 + d]);
    chan[(size_t)b * 512 + d] = acc;
}

// LayerNorm over 512. One wave per row, 4 rows/block.
// IBF: 1 = bf16 input. OBF: 1 = bf16 out.
template<int IBF, int OBF>
__global__ __launch_bounds__(256) void ln_kernel(
    const void* __restrict__ inv, const float* __restrict__ g,
    const float* __restrict__ bb, void* __restrict__ out)
{
    const size_t row = (size_t)blockIdx.x * 4 + (threadIdx.x >> 6);
    const int t = threadIdx.x & 63;
    float4 v0, v1;
    if (IBF) {
        const u16* p = (const u16*)inv + row * 512;
        uint2 a = *(const uint2*)(p + t * 4);
        uint2 b = *(const uint2*)(p + 256 + t * 4);
        v0 = make_float4(bf2f((u16)(a.x & 0xffff)), bf2f((u16)(a.x >> 16)),
                         bf2f((u16)(a.y & 0xffff)), bf2f((u16)(a.y >> 16)));
        v1 = make_float4(bf2f((u16)(b.x & 0xffff)), bf2f((u16)(b.x >> 16)),
                         bf2f((u16)(b.y & 0xffff)), bf2f((u16)(b.y >> 16)));
    } else {
        const float* p = (const float*)inv + row * 512;
        v0 = *(const float4*)(p + t * 4);
        v1 = *(const float4*)(p + 256 + t * 4);
    }
    float s = (v0.x + v0.y) + (v0.z + v0.w) + (v1.x + v1.y) + (v1.z + v1.w);
    #pragma unroll
    for (int off = 1; off < 64; off <<= 1) s += __shfl_xor(s, off);
    const float mean = s * (1.0f / 512.0f);
    float a, ss = 0.f;
    a = v0.x - mean; ss += a * a;  a = v0.y - mean; ss += a * a;
    a = v0.z - mean; ss += a * a;  a = v0.w - mean; ss += a * a;
    a = v1.x - mean; ss += a * a;  a = v1.y - mean; ss += a * a;
    a = v1.z - mean; ss += a * a;  a = v1.w - mean; ss += a * a;
    #pragma unroll
    for (int off = 1; off < 64; off <<= 1) ss += __shfl_xor(ss, off);
    const float rstd = rsqrtf(ss * (1.0f / 512.0f) + 1e-5f);
    const int c0 = t * 4, c1 = 256 + t * 4;
    float4 g0 = *(const float4*)(g + c0), g1v = *(const float4*)(g + c1);
    float4 b0 = *(const float4*)(bb + c0), b1v = *(const float4*)(bb + c1);
    float r0 = (v0.x - mean) * rstd * g0.x + b0.x;
    float r1 = (v0.y - mean) * rstd * g0.y + b0.y;
    float r2 = (v0.z - mean) * rstd * g0.z + b0.z;
    float r3 = (v0.w - mean) * rstd * g0.w + b0.w;
    float r4 = (v1.x - mean) * rstd * g1v.x + b1v.x;
    float r5 = (v1.y - mean) * rstd * g1v.y + b1v.y;
    float r6 = (v1.z - mean) * rstd * g1v.z + b1v.z;
    float r7 = (v1.w - mean) * rstd * g1v.w + b1v.w;
    if (OBF) {
        u16* ob = (u16*)out + row * 512;
        uint2 u0, u1;
        u0.x = (u32)f2bf(r0) | ((u32)f2bf(r1) << 16);
        u0.y = (u32)f2bf(r2) | ((u32)f2bf(r3) << 16);
        u1.x = (u32)f2bf(r4) | ((u32)f2bf(r5) << 16);
        u1.y = (u32)f2bf(r6) | ((u32)f2bf(r7) << 16);
        *(uint2*)(ob + c0) = u0;
        *(uint2*)(ob + c1) = u1;
    } else {
        float* of = (float*)out + row * 512;
        *(float4*)(of + c0) = make_float4(r0, r1, r2, r3);
        *(float4*)(of + c1) = make_float4(r4, r5, r6, r7);
    }
}

// ---------------------------------------------------------------------------
extern "C" void kernel_launch(void* const* d_in, const int* in_sizes, int n_in,
                              void* d_out, int out_size, void* d_ws, size_t ws_size,
                              hipStream_t stream)
{
    const float* src    = (const float*)d_in[0];
    const float* Wq     = (const float*)d_in[1];
    const float* bq     = (const float*)d_in[2];
    const float* Wk     = (const float*)d_in[3];
    const float* bk     = (const float*)d_in[4];
    const float* Wv     = (const float*)d_in[5];
    const float* bv     = (const float*)d_in[6];
    const float* Wo     = (const float*)d_in[7];
    const float* bo     = (const float*)d_in[8];
    const float* router = (const float*)d_in[9];
    const float* mexp   = (const float*)d_in[10];
    const float* pos    = (const float*)d_in[11];
    const float* g1     = (const float*)d_in[12];
    const float* b1     = (const float*)d_in[13];
    const float* Wf1    = (const float*)d_in[14];
    const float* bf1    = (const float*)d_in[15];
    const float* Wf2    = (const float*)d_in[16];
    const float* bf2_   = (const float*)d_in[17];
    const float* g2     = (const float*)d_in[18];
    const float* b2     = (const float*)d_in[19];

    float* out = (float*)d_out;   // final f32 (written by LN2)

    char* ws = (char*)d_ws;
    // ws layout (bytes). Peak ~547.4 MB (same proven budget).
    u16*   Qb     = (u16*)(ws + 0);              // 134217728
    u16*   Kb     = (u16*)(ws + 134217728);      // 134217728
    u16*   Vb     = (u16*)(ws + 268435456);      // 134217728
    u16*   srcb   = (u16*)(ws + 402653184);      // 134217728 bf16 src — LIVE
                                                 //  until Wo residual read!
    float* oc     = (float*)(ws + 536870912);    // 524288
    float* chan   = (float*)(ws + 537395200);    // 2097152
    u16*   wob    = (u16*)(ws + 541065216);      // 524288
    u16*   wf1b   = (u16*)(ws + 541589504);      // 2097152
    u16*   wf2b   = (u16*)(ws + 543686656);      // 2097152
    u16*   wqkvb  = (u16*)(ws + 545783808);      // 1572864
    float* qkvbias= (float*)(ws + 547356672);    // 6144
    u16*   routbf = (u16*)(ws + 547362816);      // 8192 (ends 547371008)
    // overlays (liveness-checked; FIX vs round 10: merged now overlays Qb,
    // NOT srcb — attn block (b,h) reads exactly the Q slice it later writes,
    // and all Q reads complete before any epilogue write [see kernel note]):
    u16*   merged = (u16*)(ws + 0);              // bf16 out_tf (over Qb)
    u16*   h1b    = (u16*)(ws + 134217728);      // bf16 h1 (over Kb; dead after attn/chan)
    u16*   xb     = (u16*)(ws + 0);              // bf16 LN1 out (over merged; dead after Wo)
    u16*   gbuf   = (u16*)(ws + 268435456);      // bf16 gelu chunk 134 MB (over Vb)
    u16*   h2b    = (u16*)(ws + 134217728);      // bf16 h2 (over h1b; dead after LN1)

    const dim3 blk(256);
    const dim3 blk512(512);
    // all f32->bf16 conversions in ONE launch (weights+router+src)
    convall_kernel<<<dim3(68612), blk, 0, stream>>>(
        src, Wq, Wk, Wv, Wo, Wf1, Wf2, router,
        srcb, wqkvb, wob, wf1b, wf2b, routbf);
    pack_bias_kernel<<<dim3(6), blk, 0, stream>>>(bq, bk, bv, qkvbias);
    // fused QKV projection: grid 512*6 = 3072
    gemm256_kernel<0, 1, 0, 1><<<dim3(3072), blk512, 0, stream>>>(
        srcb, wqkvb, qkvbias, nullptr, Qb, Kb, Vb, 131072, 1536, 512);
    // channel path (attn epilogue consumes chan)
    chan_oc_kernel<<<dim3(32, 8), dim3(1024), 0, stream>>>(Kb, Vb, routbf, oc);
    chan_combine_kernel<<<dim3(1024), dim3(512), 0, stream>>>(oc, pos, mexp, chan);
    // temporal attention (+chan) -> merged bf16 (aliases Qb; safe, see note)
    attn_mfma_kernel<<<dim3(1024, 8), blk, 0, stream>>>(Qb, Kb, Vb, chan, merged);
    // h1 = srcb + merged @ Wo^T + bo -> h1b bf16 (srcb intact now)
    gemm256_kernel<0, 1, 2, 0><<<dim3(1024), blk512, 0, stream>>>(
        merged, wob, bo, srcb, h1b, nullptr, nullptr, 131072, 512, 512);
    // x = LN1(h1) -> bf16 (over merged, which is dead after Wo)
    ln_kernel<1, 1><<<dim3(32768), blk, 0, stream>>>(h1b, g1, b1, xb);
    // FF in 4 chunks of 32768 rows (gbuf L3-resident between FF1/FF2)
    for (int c = 0; c < 4; ++c) {
        const size_t off = (size_t)c * 32768 * 512;
        // g = gelu(x @ Wf1^T + bf1) -> gbuf bf16; grid 128*8 = 1024
        gemm256_kernel<1, 1, 0, 0><<<dim3(1024), blk512, 0, stream>>>(
            xb + off, wf1b, bf1, nullptr, gbuf, nullptr, nullptr,
            32768, 2048, 512);
        // h2 = x + g @ Wf2^T + bf2 -> h2b bf16; grid 128*2 = 256
        gemm256_kernel<0, 1, 2, 0><<<dim3(256), blk512, 0, stream>>>(
            gbuf, wf2b, bf2_, xb + off, h2b + off, nullptr, nullptr,
            32768, 512, 2048);
    }
    // out = LN2(h2) -> d_out f32
    ln_kernel<1, 0><<<dim3(32768), blk, 0, stream>>>(h2b, g2, b2, out);
}